// Round 1
// baseline (161.366 us; speedup 1.0000x reference)
//
#include <hip/hip_runtime.h>
#include <math.h>

#define D_DIM 2048
#define N_EXP 64
#define TOPK_G 4
#define TOPK 8

#define WAVES 8
#define THREADS (WAVES * 64)
#define ROWS_PER_WG 64
#define D_PER_WAVE (D_DIM / WAVES) // 256

// Kernel 0: transpose W[E][D] -> Wt[D][E] so per-d expert rows are contiguous
// (enables wave-uniform scalar loads of W in the main kernel).
__global__ void transpose_w(const float* __restrict__ W, float* __restrict__ Wt) {
    int t = blockIdx.x * blockDim.x + threadIdx.x; // 0..131071
    if (t < N_EXP * D_DIM) {
        int d = t >> 6;  // t / 64
        int e = t & 63;
        Wt[t] = W[e * D_DIM + d];
    }
}

__launch_bounds__(THREADS, 2)
__global__ void router_kernel(const float* __restrict__ x,
                              const float* __restrict__ Wt,
                              const float* __restrict__ bias,
                              float* __restrict__ out_idx,
                              float* __restrict__ out_w) {
    __shared__ float red[WAVES][64][16]; // 32 KB reduction staging
    __shared__ float sc[64][N_EXP];      // 16 KB final scores
    __shared__ float bias_s[N_EXP];

    const int tid = threadIdx.x;
    const int wave = __builtin_amdgcn_readfirstlane(tid >> 6); // force uniform
    const int lane = tid & 63;
    const int row = blockIdx.x * ROWS_PER_WG + lane;

    if (tid < N_EXP) bias_s[tid] = bias[tid];

    float acc[N_EXP];
#pragma unroll
    for (int e = 0; e < N_EXP; ++e) acc[e] = 0.f;

    // lane = row; this wave covers d in [wave*256, wave*256+256)
    const float4* xrow = (const float4*)(x + (size_t)row * D_DIM + wave * D_PER_WAVE);
    const float* wt = Wt + (size_t)(wave * D_PER_WAVE) * N_EXP;

    for (int dq = 0; dq < D_PER_WAVE / 4; ++dq) { // 64 iterations
        float4 xv = xrow[dq];
        const float* wq = wt + dq * 4 * N_EXP; // wave-uniform -> s_load
#pragma unroll
        for (int e = 0; e < N_EXP; ++e) {
            acc[e] = fmaf(xv.x, wq[e], acc[e]);
            acc[e] = fmaf(xv.y, wq[N_EXP + e], acc[e]);
            acc[e] = fmaf(xv.z, wq[2 * N_EXP + e], acc[e]);
            acc[e] = fmaf(xv.w, wq[3 * N_EXP + e], acc[e]);
        }
    }

    // cross-wave reduction, 4 chunks of 16 experts (keeps LDS <= 64 KB)
#pragma unroll
    for (int c = 0; c < 4; ++c) {
        __syncthreads();
#pragma unroll
        for (int j = 0; j < 16; ++j) red[wave][lane][j] = acc[c * 16 + j];
        __syncthreads();
#pragma unroll
        for (int t2 = 0; t2 < 2; ++t2) {
            int idx = tid + t2 * THREADS; // 0..1023 covers 64 rows x 16 experts
            int r = idx >> 4, j = idx & 15;
            float s = 0.f;
#pragma unroll
            for (int w = 0; w < WAVES; ++w) s += red[w][r][j];
            sc[r][c * 16 + j] = s;
        }
    }
    __syncthreads();

    // sigmoid in place (precise expf: monotone map, minimal tie-collapse risk)
#pragma unroll
    for (int t2 = 0; t2 < 8; ++t2) {
        int idx = tid + t2 * THREADS;
        int r = idx >> 6, e = idx & 63;
        float v = sc[r][e];
        sc[r][e] = 1.0f / (1.0f + expf(-v));
    }
    __syncthreads();

    // per-row selection: thread r handles row r (serial; trivial vs GEMM cost)
    if (tid < ROWS_PER_WG) {
        const int r = tid;
        // group max over biased scores
        float gmax[8];
#pragma unroll
        for (int g = 0; g < 8; ++g) {
            float m = -INFINITY;
#pragma unroll
            for (int j = 0; j < 8; ++j) {
                float v = sc[r][g * 8 + j] + bias_s[g * 8 + j];
                m = fmaxf(m, v);
            }
            gmax[g] = m;
        }
        // top-4 groups (stable: strict >, ascending scan -> lowest index wins ties)
        unsigned gsel = 0;
        for (int k = 0; k < TOPK_G; ++k) {
            int best = 0; float bv = -INFINITY;
#pragma unroll
            for (int g = 0; g < 8; ++g) {
                if (!((gsel >> g) & 1) && gmax[g] > bv) { bv = gmax[g]; best = g; }
            }
            gsel |= 1u << best;
        }
        unsigned long long emask = 0ull;
#pragma unroll
        for (int g = 0; g < 8; ++g)
            if ((gsel >> g) & 1) emask |= (0xFFull << (g * 8));
        // top-8 experts among selected groups (stable)
        int idx[TOPK];
        float wv[TOPK];
        unsigned long long esel = 0ull;
        for (int k = 0; k < TOPK; ++k) {
            int best = 0; float bv = -INFINITY;
            for (int e = 0; e < N_EXP; ++e) {
                if (((emask >> e) & 1) && !((esel >> e) & 1)) {
                    float v = sc[r][e] + bias_s[e];
                    if (v > bv) { bv = v; best = e; }
                }
            }
            esel |= 1ull << best;
            idx[k] = best;
        }
        float wsum = 0.f;
#pragma unroll
        for (int k = 0; k < TOPK; ++k) { wv[k] = sc[r][idx[k]]; wsum += wv[k]; }
        float inv = 1.0f / (wsum + 1e-20f);
        int grow = blockIdx.x * ROWS_PER_WG + r;
#pragma unroll
        for (int k = 0; k < TOPK; ++k) {
            out_idx[grow * TOPK + k] = (float)idx[k]; // indices as float32
            out_w[grow * TOPK + k] = wv[k] * inv;
        }
    }
}

extern "C" void kernel_launch(void* const* d_in, const int* in_sizes, int n_in,
                              void* d_out, int out_size, void* d_ws, size_t ws_size,
                              hipStream_t stream) {
    const float* x = (const float*)d_in[0];
    const float* W = (const float*)d_in[1];
    const float* bias = (const float*)d_in[2];
    float* out = (float*)d_out;
    float* Wt = (float*)d_ws; // 2048*64*4 = 512 KB scratch

    hipLaunchKernelGGL(transpose_w, dim3((N_EXP * D_DIM + 255) / 256), dim3(256), 0, stream,
                       W, Wt);
    const int n_wg = 16384 / ROWS_PER_WG; // 256
    hipLaunchKernelGGL(router_kernel, dim3(n_wg), dim3(THREADS), 0, stream,
                       x, Wt, bias, out, out + 16384 * TOPK);
}

// Round 2
// 105.966 us; speedup vs baseline: 1.5228x; 1.5228x over previous
//
#include <hip/hip_runtime.h>
#include <math.h>

#define N_EXP 64
#define TOPK 8
#define TOPK_G 4
#define D_DIM 2048
#define BM 64
#define WAVES 8
#define THREADS 512
#define KW (D_DIM / WAVES)   // 256 k per wave
#define BK 8                 // k per staged chunk
#define NCHUNK (KW / BK)     // 32

// LDS map (floats), total 8192 floats = 32 KB:
//   GEMM phase : per-wave staging at [wave*1024]: x chunk [BK][64] then W chunk [BK][64]
//   Reduce     : part[2][64][64] at [p*4096], e-col swizzled by (4*(r>>3))&63
//   Final      : sc[64][68] at [0], biased-bias copy at [4400]
__launch_bounds__(THREADS)
__global__ void router_kernel(const float* __restrict__ x,
                              const float* __restrict__ W,
                              const float* __restrict__ bias,
                              float* __restrict__ out_idx,
                              float* __restrict__ out_w)
{
    __shared__ float smem[8192];

    const int tid  = threadIdx.x;
    const int wave = tid >> 6;
    const int lane = tid & 63;
    const int lm   = lane >> 3;   // row-group 0..7   (thread rows  = lm*8 + i)
    const int ln   = lane & 7;    // expert-group 0..7 (thread exps = ln*8 + j)
    const int row0 = blockIdx.x * BM;
    const int base = wave * 1024;

    // staging sources: lane = row for x, lane = expert for W; both walk this
    // wave's k-window [wave*KW, wave*KW+KW)
    const float* xrow = x + (size_t)(row0 + lane) * D_DIM + wave * KW;
    const float* wrow = W + (size_t)lane * D_DIM + wave * KW;

    float acc[8][8];
#pragma unroll
    for (int i = 0; i < 8; ++i)
#pragma unroll
        for (int j = 0; j < 8; ++j) acc[i][j] = 0.f;

    // ---- prologue: stage chunk 0 (global -> reg -> LDS, transposed) ----
    {
        float4 a0 = *(const float4*)(xrow);
        float4 a1 = *(const float4*)(xrow + 4);
        float4 b0 = *(const float4*)(wrow);
        float4 b1 = *(const float4*)(wrow + 4);
        smem[base + 0 * 64 + lane] = a0.x; smem[base + 1 * 64 + lane] = a0.y;
        smem[base + 2 * 64 + lane] = a0.z; smem[base + 3 * 64 + lane] = a0.w;
        smem[base + 4 * 64 + lane] = a1.x; smem[base + 5 * 64 + lane] = a1.y;
        smem[base + 6 * 64 + lane] = a1.z; smem[base + 7 * 64 + lane] = a1.w;
        smem[base + 512 + 0 * 64 + lane] = b0.x; smem[base + 512 + 1 * 64 + lane] = b0.y;
        smem[base + 512 + 2 * 64 + lane] = b0.z; smem[base + 512 + 3 * 64 + lane] = b0.w;
        smem[base + 512 + 4 * 64 + lane] = b1.x; smem[base + 512 + 5 * 64 + lane] = b1.y;
        smem[base + 512 + 6 * 64 + lane] = b1.z; smem[base + 512 + 7 * 64 + lane] = b1.w;
    }

    // ---- main loop: wave-private single buffer, reg-prefetch next chunk ----
    for (int c = 0; c < NCHUNK; ++c) {
        float4 nx0, nx1, nw0, nw1;
        const bool pf = (c + 1 < NCHUNK);
        if (pf) {
            const float* xp = xrow + (c + 1) * BK;
            const float* wp = wrow + (c + 1) * BK;
            nx0 = *(const float4*)(xp);
            nx1 = *(const float4*)(xp + 4);
            nw0 = *(const float4*)(wp);
            nw1 = *(const float4*)(wp + 4);
        }
#pragma unroll
        for (int k = 0; k < BK; ++k) {
            float fx[8], fw[8];
            *(float4*)&fx[0] = *(const float4*)&smem[base + k * 64 + lm * 8];
            *(float4*)&fx[4] = *(const float4*)&smem[base + k * 64 + lm * 8 + 4];
            *(float4*)&fw[0] = *(const float4*)&smem[base + 512 + k * 64 + ln * 8];
            *(float4*)&fw[4] = *(const float4*)&smem[base + 512 + k * 64 + ln * 8 + 4];
#pragma unroll
            for (int i = 0; i < 8; ++i)
#pragma unroll
                for (int j = 0; j < 8; ++j)
                    acc[i][j] = fmaf(fx[i], fw[j], acc[i][j]);
        }
        if (pf) {
            smem[base + 0 * 64 + lane] = nx0.x; smem[base + 1 * 64 + lane] = nx0.y;
            smem[base + 2 * 64 + lane] = nx0.z; smem[base + 3 * 64 + lane] = nx0.w;
            smem[base + 4 * 64 + lane] = nx1.x; smem[base + 5 * 64 + lane] = nx1.y;
            smem[base + 6 * 64 + lane] = nx1.z; smem[base + 7 * 64 + lane] = nx1.w;
            smem[base + 512 + 0 * 64 + lane] = nw0.x; smem[base + 512 + 1 * 64 + lane] = nw0.y;
            smem[base + 512 + 2 * 64 + lane] = nw0.z; smem[base + 512 + 3 * 64 + lane] = nw0.w;
            smem[base + 512 + 4 * 64 + lane] = nw1.x; smem[base + 512 + 5 * 64 + lane] = nw1.y;
            smem[base + 512 + 6 * 64 + lane] = nw1.z; smem[base + 512 + 7 * 64 + lane] = nw1.w;
        }
    }

    // ---- cross-wave k-reduction: 4 rounds of 2 waves into part[2][64][64] ----
    float red[8];
#pragma unroll
    for (int j = 0; j < 8; ++j) red[j] = 0.f;
    const int r2 = tid >> 3;          // reduction row 0..63
    const int e0 = (tid & 7) * 8;     // reduction expert base
    const int rsw = 4 * (r2 >> 3);    // reader swizzle

    for (int rj = 0; rj < 4; ++rj) {
        __syncthreads();
        if ((wave >> 1) == rj) {
            const int p = wave & 1;
#pragma unroll
            for (int i = 0; i < 8; ++i) {
                const int r = lm * 8 + i;
#pragma unroll
                for (int q = 0; q < 2; ++q) {
                    const int ec = (ln * 8 + q * 4 + 4 * lm) & 63; // writer swizzle
                    *(float4*)&smem[p * 4096 + r * 64 + ec] =
                        make_float4(acc[i][q * 4 + 0], acc[i][q * 4 + 1],
                                    acc[i][q * 4 + 2], acc[i][q * 4 + 3]);
                }
            }
        }
        __syncthreads();
#pragma unroll
        for (int p = 0; p < 2; ++p) {
#pragma unroll
            for (int q = 0; q < 2; ++q) {
                const int ec = (e0 + q * 4 + rsw) & 63;
                const float4 v = *(const float4*)&smem[p * 4096 + r2 * 64 + ec];
                red[q * 4 + 0] += v.x; red[q * 4 + 1] += v.y;
                red[q * 4 + 2] += v.z; red[q * 4 + 3] += v.w;
            }
        }
    }

    __syncthreads(); // part region reads done; safe to overwrite with sc/bias

    // sigmoid in registers, write sc[64][68] (padded) + stage bias
    {
        float sg[8];
#pragma unroll
        for (int j = 0; j < 8; ++j) sg[j] = 1.0f / (1.0f + expf(-red[j]));
        *(float4*)&smem[r2 * 68 + e0]     = make_float4(sg[0], sg[1], sg[2], sg[3]);
        *(float4*)&smem[r2 * 68 + e0 + 4] = make_float4(sg[4], sg[5], sg[6], sg[7]);
    }
    if (tid >= 448) smem[4400 + (tid - 448)] = bias[tid - 448];
    __syncthreads();

    // ---- selection: thread r handles row r (proven R1 logic) ----
    if (tid < BM) {
        const int r = tid;
        float gmax[8];
#pragma unroll
        for (int g = 0; g < 8; ++g) {
            float m = -INFINITY;
#pragma unroll
            for (int j = 0; j < 8; ++j) {
                float v = smem[r * 68 + g * 8 + j] + smem[4400 + g * 8 + j];
                m = fmaxf(m, v);
            }
            gmax[g] = m;
        }
        unsigned gsel = 0;
        for (int k = 0; k < TOPK_G; ++k) {
            int best = 0; float bv = -INFINITY;
#pragma unroll
            for (int g = 0; g < 8; ++g)
                if (!((gsel >> g) & 1) && gmax[g] > bv) { bv = gmax[g]; best = g; }
            gsel |= 1u << best;
        }
        unsigned long long emask = 0ull;
#pragma unroll
        for (int g = 0; g < 8; ++g)
            if ((gsel >> g) & 1) emask |= (0xFFull << (g * 8));

        const int grow = row0 + r;
        unsigned long long esel = 0ull;
        float wsum = 0.f;
        for (int k = 0; k < TOPK; ++k) {
            int best = 0; float bv = -INFINITY;
            for (int e = 0; e < N_EXP; ++e) {
                if (((emask >> e) & 1) && !((esel >> e) & 1)) {
                    float v = smem[r * 68 + e] + smem[4400 + e];
                    if (v > bv) { bv = v; best = e; }
                }
            }
            esel |= 1ull << best;
            const float w8 = smem[r * 68 + best];
            out_idx[grow * TOPK + k] = (float)best;
            out_w[grow * TOPK + k]  = w8;
            wsum += w8;
        }
        const float inv = 1.0f / (wsum + 1e-20f);
        for (int k = 0; k < TOPK; ++k)
            out_w[grow * TOPK + k] *= inv;
    }
}

extern "C" void kernel_launch(void* const* d_in, const int* in_sizes, int n_in,
                              void* d_out, int out_size, void* d_ws, size_t ws_size,
                              hipStream_t stream) {
    const float* x    = (const float*)d_in[0];
    const float* W    = (const float*)d_in[1];
    const float* bias = (const float*)d_in[2];
    float* out = (float*)d_out;

    const int n_wg = 16384 / BM; // 256
    hipLaunchKernelGGL(router_kernel, dim3(n_wg), dim3(THREADS), 0, stream,
                       x, W, bias, out, out + 16384 * TOPK);
}